// Round 3
// baseline (226.463 us; speedup 1.0000x reference)
//
#include <hip/hip_runtime.h>

// CIN cross-network, fused MFMA implementation (f16 inputs, fp32 accum).
// Round 6: switch 16x16x32 -> 32x32x16 MFMA, packing TWO batches along the
// 32-row axis (rows 0-15 = batch pair-lo d0..15, rows 16-31 = pair-hi).
//  - 2x FLOP per MFMA instruction at the higher 2382 TF ceiling (vs 2075).
//  - per kb: 2 B-loads + 8 pk_mul + 4 MFMA (~8 issue slots / 65 kFLOP) vs
//    round-5's ~12 -> attacks the measured 96% combined issue saturation.
//  - W read traffic from L2 halves (B fragment shared by 2 batches).
// Carried over verified structure: 256-thr blocks, 4 waves x 4 private
// batches, m-major x0 (round-5 conflict fix), d-major xk, no barriers.
//
// Fragment layouts (32x32x16 f16):
//   A[row][k]: row = lane&31, k = (lane>>5)*8 + j      (j = half index 0..7)
//   B[k][col]: col = lane&31, k = (lane>>5)*8 + j
//   C/D:       col = lane&31, row = (reg&3) + 8*(reg>>2) + 4*(lane>>5)
// (C/D is the HW-verified m74/m101 mapping; A/B mirror our verified
//  16x16x32 mapping with lane>>4 -> lane>>5.)

typedef _Float16 half8 __attribute__((ext_vector_type(8)));
typedef _Float16 half4 __attribute__((ext_vector_type(4)));
typedef _Float16 half2v __attribute__((ext_vector_type(2)));
typedef float f32x16 __attribute__((ext_vector_type(16)));

#define OUT_STRIDE 192
#define X0B 512   // x0 batch stride (m-major: m*16 + d, 32x16 halfs)
#define XKR 72    // xk row stride: 64 + 8 pad (16B-aligned)
#define XKB 1152  // xk batch stride

// ---------------------------------------------------------------------------
// Fused weight repack for 32x32x16 B-fragments:
// dst[((t*NKB + kb)*64 + lane)*8 + j] = (f16) W[k -> (m,h)][n],
//   k = kb*16 + (lane>>5)*8 + j,  n = t*32 + (lane&31),  t in {0,1}.
__global__ void prep_w_all(const float* __restrict__ W0,
                           const float* __restrict__ W1,
                           const float* __restrict__ W2,
                           _Float16* __restrict__ dst) {
  int e = blockIdx.x * 256 + threadIdx.x;   // e < 327680
  const float* W;
  int logH, nkbLog, le;
  if (e < 65536)       { W = W0; logH = 5; nkbLog = 6; le = e; }
  else if (e < 196608) { W = W1; logH = 6; nkbLog = 7; le = e - 65536; }
  else                 { W = W2; logH = 6; nkbLog = 7; le = e - 196608; }
  int j    = le & 7;
  int lane = (le >> 3) & 63;
  int rest = le >> 9;
  int kb   = rest & ((1 << nkbLog) - 1);
  int t    = rest >> nkbLog;
  int k    = kb * 16 + ((lane >> 5) << 3) + j;
  int H    = 1 << logH;
  int m    = k >> logH, h = k & (H - 1);
  int n    = t * 32 + (lane & 31);
  dst[e] = (_Float16)W[(m * H + h) * 64 + n];
}

// ---------------------------------------------------------------------------
// One layer for one wave's 4 private batches (2 pairs of 2).
// NHB: 16-wide h-blocks per m (2 for H=32, 1st layer; 4 for H=64).
// NKB = 32*NHB K-blocks of 16.
// av[p][mh] = xk 8-vector at h = mh*16 + (lane>>5)*8 + j, d = lane&15,
//             batch = p*2 + ((lane>>4)&1), held in registers.
// x0s is M-MAJOR: x0s[b*X0B + m*16 + d].
template<int NHB, bool LAST>
__device__ __forceinline__ void run_layer32(
    const _Float16* __restrict__ Wp, const half8 (&av)[2][NHB],
    const _Float16* x0s, _Float16* xkw, float* __restrict__ out,
    long gb0, int loff, int lane, int dl, int pb, int kg)
{
  const int NKB = 32 * NHB;
  f32x16 acc[2][2];
#pragma unroll
  for (int p = 0; p < 2; ++p)
#pragma unroll
    for (int t = 0; t < 2; ++t)
#pragma unroll
      for (int rr = 0; rr < 16; ++rr) acc[p][t][rr] = 0.f;

  const _Float16* Wl = Wp + lane * 8;
  const _Float16* x0l = x0s + pb * X0B + dl;   // this lane's batch within pair

#pragma unroll 2
  for (int m = 0; m < 32; ++m) {
    // x0 scalar per pair for this m (m-major: 16 consecutive u16 per group,
    // 2-way conflict between the pb halves -> free).
    half2v xs2[2];
#pragma unroll
    for (int p = 0; p < 2; ++p) {
      _Float16 x = x0l[p * 2 * X0B + m * 16];
      xs2[p] = (half2v){x, x};
    }
#pragma unroll
    for (int mh = 0; mh < NHB; ++mh) {
      const int kb = m * NHB + mh;
      half8 Bf0 = *(const half8*)(Wl + (size_t)(0 * NKB + kb) * 512);
      half8 Bf1 = *(const half8*)(Wl + (size_t)(1 * NKB + kb) * 512);
#pragma unroll
      for (int p = 0; p < 2; ++p) {
        half8 af;
        half2v* ap = (half2v*)&af;
        const half2v* vp = (const half2v*)&av[p][mh];
#pragma unroll
        for (int j2 = 0; j2 < 4; ++j2) ap[j2] = vp[j2] * xs2[p];
        acc[p][0] = __builtin_amdgcn_mfma_f32_32x32x16_f16(af, Bf0, acc[p][0], 0, 0, 0);
        acc[p][1] = __builtin_amdgcn_mfma_f32_32x32x16_f16(af, Bf1, acc[p][1], 0, 0, 0);
      }
    }
  }

  // Epilogue. C/D: col n = lane&31, row = (reg&3)+8*(reg>>2)+4*kg;
  // row>>4 = reg>>3 selects batch within pair, d = row&15.
#pragma unroll
  for (int p = 0; p < 2; ++p) {
#pragma unroll
    for (int t = 0; t < 2; ++t) {
      float s0 = 0.f, s1 = 0.f;
#pragma unroll
      for (int reg = 0; reg < 16; ++reg) {
        float v = acc[p][t][reg];
        v = v > 0.f ? v : 0.f;
        const int pbq = reg >> 3;
        const int d = (reg & 3) + 8 * ((reg >> 2) & 1) + 4 * kg;
        if (!LAST)
          xkw[(p * 2 + pbq) * XKB + d * XKR + t * 32 + (lane & 31)] = (_Float16)v;
        if (pbq == 0) s0 += v; else s1 += v;
      }
      s0 += __shfl_xor(s0, 32);
      s1 += __shfl_xor(s1, 32);
      if (kg == 0) {   // lanes 0..31, n = lane
        out[(gb0 + p * 2 + 0) * OUT_STRIDE + loff + t * 32 + lane] = s0;
        out[(gb0 + p * 2 + 1) * OUT_STRIDE + loff + t * 32 + lane] = s1;
      }
    }
  }
}

__global__ __launch_bounds__(256, 3) void cin_main(
    const float* __restrict__ emb, const _Float16* __restrict__ Wall,
    float* __restrict__ out)
{
  // x0: 16 batches * 512 f16 (m-major) = 16384 B
  // xk: 16 batches * 1152 f16 (16 d rows of stride 72) = 36864 B
  // total 53248 B -> 3 blocks/CU.
  __shared__ __align__(16) _Float16 lds[16 * X0B + 16 * XKB];
  const int lane = threadIdx.x & 63;
  const int wv = threadIdx.x >> 6;
  const int dl = lane & 15;            // d for A/av reads
  const int pb = (lane >> 4) & 1;      // batch-within-pair for A rows
  const int kg = lane >> 5;            // K-group
  const long gb0 = (long)blockIdx.x * 16 + wv * 4;

  _Float16* x0w = &lds[wv * 4 * X0B];
  _Float16* xkw = &lds[16 * X0B + wv * 4 * XKB];

  // Stage this wave's 4 batches: emb is (m,d) row-major = the LDS layout.
#pragma unroll
  for (int bb = 0; bb < 4; ++bb) {
    const float* src = emb + (gb0 + bb) * 512;
    _Float16* dstb = x0w + bb * X0B;
#pragma unroll
    for (int i = 0; i < 2; ++i) {
      int f = i * 256 + lane * 4;
      float4 v = *(const float4*)(src + f);
      half4 h = {(_Float16)v.x, (_Float16)v.y, (_Float16)v.z, (_Float16)v.w};
      *(half4*)(dstb + f) = h;
    }
  }
  // All LDS regions are wave-private: program order + waitcnt suffice.

  // Layer 1: av from x0 (xk==x0; h indexes the m-major m axis).
  // One-time strided u16 gathers.
  half8 av1[2][2];
#pragma unroll
  for (int p = 0; p < 2; ++p)
#pragma unroll
    for (int mh = 0; mh < 2; ++mh)
#pragma unroll
      for (int j = 0; j < 8; ++j)
        av1[p][mh][j] =
            x0w[(p * 2 + pb) * X0B + (mh * 16 + kg * 8 + j) * 16 + dl];
  run_layer32<2, false>(Wall, av1, x0w, xkw, out, gb0, 0, lane, dl, pb, kg);

  // Layer 2: av from xk (d-major [d][h]); aligned half8 reads.
  half8 av2[2][4];
#pragma unroll
  for (int p = 0; p < 2; ++p)
#pragma unroll
    for (int mh = 0; mh < 4; ++mh)
      av2[p][mh] = *(const half8*)(xkw + (p * 2 + pb) * XKB + dl * XKR +
                                   mh * 16 + kg * 8);
  run_layer32<4, false>(Wall + 65536, av2, x0w, xkw, out, gb0, 64, lane, dl, pb, kg);

  // Layer 3: reload av (layer 2 rewrote xk).
#pragma unroll
  for (int p = 0; p < 2; ++p)
#pragma unroll
    for (int mh = 0; mh < 4; ++mh)
      av2[p][mh] = *(const half8*)(xkw + (p * 2 + pb) * XKB + dl * XKR +
                                   mh * 16 + kg * 8);
  run_layer32<4, true>(Wall + 196608, av2, x0w, xkw, out, gb0, 128, lane, dl, pb, kg);
}

extern "C" void kernel_launch(void* const* d_in, const int* in_sizes, int n_in,
                              void* d_out, int out_size, void* d_ws, size_t ws_size,
                              hipStream_t stream) {
  const float* emb = (const float*)d_in[0];
  const float* W0  = (const float*)d_in[1];
  const float* W1  = (const float*)d_in[2];
  const float* W2  = (const float*)d_in[3];
  float* out = (float*)d_out;
  _Float16* ws = (_Float16*)d_ws;   // needs 327680 f16 = 640 KB

  // Single fused weight repack (327680 elements).
  prep_w_all<<<1280, 256, 0, stream>>>(W0, W1, W2, ws);

  // 16384 batches / 16 per block = 1024 blocks of 256 threads (4 waves x 4 b).
  cin_main<<<1024, 256, 0, stream>>>(emb, ws, out);
}